// Round 12
// baseline (182.846 us; speedup 1.0000x reference)
//
#include <hip/hip_runtime.h>
#include <hip/hip_bf16.h>
#include <stdint.h>
#include <stddef.h>

typedef __bf16 bf16;
typedef __attribute__((ext_vector_type(8))) __bf16 bf16x8;
typedef __attribute__((ext_vector_type(4))) __bf16 bf16x4;
typedef __attribute__((ext_vector_type(2))) __bf16 bf16x2;
typedef __attribute__((ext_vector_type(4))) float f32x4;

#define MFMA16(a, b, c) __builtin_amdgcn_mfma_f32_16x16x32_bf16(a, b, c, 0, 0, 0)

#define BB 2
#define SEQ 2048
#define FDIM 1024
#define NH 16
#define HD 64
#define M_TOK 4096   /* BB*SEQ */
#define N_QKV 3072   /* 3*FDIM */

#define CSC 0.04508422f  /* (1/32) * log2(e) — folded into Wq/bq */

// async global->LDS, 16B per lane; LDS dest is wave-uniform base + lane*16
__device__ __forceinline__ void gll16(const bf16* g, bf16* l) {
    __builtin_amdgcn_global_load_lds(
        (const __attribute__((address_space(1))) void*)g,
        (__attribute__((address_space(3))) void*)l, 16, 0, 0);
}

// fast f32 -> bf16 (round-to-nearest; 2 VALU ops)
__device__ __forceinline__ bf16 pack_bf16(float f) {
    uint32_t u = __builtin_bit_cast(uint32_t, f);
    uint16_t h = (uint16_t)((u + 0x8000u) >> 16);
    return __builtin_bit_cast(bf16, h);
}

// pack two f32 -> one dword of two bf16 (lo=a, hi=b)
__device__ __forceinline__ uint32_t pk2(float a, float b) {
#if __has_builtin(__builtin_amdgcn_cvt_pk_bf16_f32)
    bf16x2 t = __builtin_amdgcn_cvt_pk_bf16_f32(a, b);
    return __builtin_bit_cast(uint32_t, t);
#else
    uint32_t ua = __builtin_bit_cast(uint32_t, a) + 0x8000u;
    uint32_t ub = __builtin_bit_cast(uint32_t, b) + 0x8000u;
    return __builtin_amdgcn_perm(ub, ua, 0x07060302);
#endif
}

// ---------------------------------------------------------------------------
// fp32 -> bf16 conversion; Wq/bq pre-scaled by CSC.
// ---------------------------------------------------------------------------
__global__ __launch_bounds__(256) void convert_k(
    const float* __restrict__ x,
    const float* __restrict__ Wq, const float* __restrict__ bq,
    const float* __restrict__ Wk, const float* __restrict__ bk,
    const float* __restrict__ Wv, const float* __restrict__ bv,
    const float* __restrict__ Wo,
    bf16* __restrict__ xb, bf16* __restrict__ Wcat, bf16* __restrict__ Wob,
    float* __restrict__ bcat)
{
    const int tid = blockIdx.x * blockDim.x + threadIdx.x;
    const int nt = gridDim.x * blockDim.x;
    const int NX4 = M_TOK * FDIM / 4;
    const int NW4 = FDIM * FDIM / 4;

    for (int i = tid; i < NX4; i += nt) {
        float4 v = ((const float4*)x)[i];
        bf16x4 o; o[0] = (bf16)v.x; o[1] = (bf16)v.y; o[2] = (bf16)v.z; o[3] = (bf16)v.w;
        ((bf16x4*)xb)[i] = o;
    }
    for (int i = tid; i < NW4; i += nt) {
        float4 v = ((const float4*)Wq)[i];
        bf16x4 o;
        o[0] = (bf16)(v.x * CSC); o[1] = (bf16)(v.y * CSC);
        o[2] = (bf16)(v.z * CSC); o[3] = (bf16)(v.w * CSC);
        ((bf16x4*)Wcat)[i] = o;
        v = ((const float4*)Wk)[i];
        o[0] = (bf16)v.x; o[1] = (bf16)v.y; o[2] = (bf16)v.z; o[3] = (bf16)v.w;
        ((bf16x4*)Wcat)[NW4 + i] = o;
        v = ((const float4*)Wv)[i];
        o[0] = (bf16)v.x; o[1] = (bf16)v.y; o[2] = (bf16)v.z; o[3] = (bf16)v.w;
        ((bf16x4*)Wcat)[2 * NW4 + i] = o;
        v = ((const float4*)Wo)[i];
        o[0] = (bf16)v.x; o[1] = (bf16)v.y; o[2] = (bf16)v.z; o[3] = (bf16)v.w;
        ((bf16x4*)Wob)[i] = o;
    }
    for (int i = tid; i < FDIM; i += nt) {
        bcat[i] = bq[i] * CSC;
        bcat[FDIM + i] = bk[i];
        bcat[2 * FDIM + i] = bv[i];
    }
}

// ---------------------------------------------------------------------------
// gemm_qkv (QKV projection, m201-class schedule): BM=BN=256, BK=64,
// grid 192 blocks (XCD-swizzled; 192%8==0 -> bijective), 8 waves (2Mx4N),
// per-wave 128x64 C (acc[8][4]).  LDS 2 slots x (A 32KB | B 32KB) = 128KB,
// 1 block/CU.
// 4 sub-phases/K-tile, each: {ds_read A-frags (+B at ph0) | stage one
// region of tile t+1 -> s_barrier -> lgkmcnt(0)+sched_barrier ->
// setprio(1) 16 MFMA setprio(0) -> [counted vmcnt gate] -> s_barrier}.
// REGIONS: A in 4 quarters (64 rows, 1 gll16/wave), B in 2 halves
// (128 cols, 2 gll16/wave).  Stage order during tile t (slot ns, dead
// data): ph0: q0,q2 | ph1: B0c0,B0c1,B1c0,B1c1 | ph2: q1,q3.
// CONSUMPTION (per wave wr,wc): ph0/ph1 read quarter wr*2 (q0 or q2) +
// B-half wc>>1 (both halves across waves); ph2/ph3 read quarter wr*2+1
// (q1 or q3).  GATE TRACE (per-thread outstanding, oldest first):
//  - end-ph1: [q1,q3 of t (issued t-1 ph2)] + [6 of t+1] = 8 ->
//    vmcnt(6) waits q1,q3 (window ~3 phases) -> ph2/ph3 reads safe.
//  - end-ph3: [8 of t+1] -> vmcnt(2) waits q0,q2,B0,B1 (issued ph0/ph1,
//    window 2-3 phases) -> next tile's ph0/ph1 reads safe; q1,q3(t+1)
//    stay in flight.  Gates sit immediately before a barrier -> all
//    waves' contributions landed.  Last tile: pf=false -> vmcnt(0).
// T2 XOR swizzle (phys 16B slot = logical ^ (row&7); inverse on source).
// Epilogue: block-uniform V branch (n0 multiple of 256; V = n0>=2048).
// ---------------------------------------------------------------------------
__global__ __launch_bounds__(512, 2) void gemm_qkv(
    const bf16* __restrict__ A,    // M x K
    const bf16* __restrict__ Bw,   // N x K
    const float* __restrict__ bias,// N
    bf16* __restrict__ Cb,         // bf16 out
    bf16* __restrict__ VtOut,      // transposed-V output (cols >= 2048)
    int M, int N, int K)
{
    extern __shared__ char smem[];          // 131072
    const int tid = threadIdx.x;
    const int lane = tid & 63;
    const int wave = tid >> 6;              // 0..7
    const int wr = wave >> 2;               // 0..1 : rows [wr*128,+128)
    const int wc = wave & 3;                // 0..3 : cols [wc*64,+64)
    // XCD swizzle: 192 = 8 x 24 (bijective)
    const int lin = (blockIdx.x & 7) * 24 + (blockIdx.x >> 3);
    const int m0 = (lin / 12) * 256;
    const int n0 = (lin % 12) * 256;
    const int lrow = lane & 15;
    const int quad = lane >> 4;
    const int NT = K >> 6;

    const int l8 = lane >> 3;
    const int kx = ((lane & 7) ^ l8) << 3;  // inverse-swizzled source k offset

#define AQ(sl, kt, q) gll16(A + (size_t)(m0 + (q) * 64 + wave * 8 + l8) * K \
        + (size_t)(kt) * 64 + kx, \
        (bf16*)(smem + (sl) * 65536 + (q) * 8192 + wave * 1024))
#define BH(sl, kt, h, c) gll16(Bw + (size_t)(n0 + (h) * 128 + wave * 16 + (c) * 8 + l8) * K \
        + (size_t)(kt) * 64 + kx, \
        (bf16*)(smem + (sl) * 65536 + 32768 + (h) * 16384 + wave * 2048 + (c) * 1024))

    const int swz0 = ((quad ^ (lrow & 7)) << 4);
    const int swz1 = (((4 + quad) ^ (lrow & 7)) << 4);
    const int abase = (wr * 2) * 8192 + lrow * 128;
    const int bbase = 32768 + (wc >> 1) * 16384 + ((wc & 1) * 64 + lrow) * 128;

    f32x4 acc[8][4] = {};
    bf16x8 bfr[4][2];   // [jq][ks], cached across the tile's 4 phases

    // prologue: tile 0, issue order matches steady state (q0,q2,B...,q1,q3)
    AQ(0, 0, 0); AQ(0, 0, 2);
    BH(0, 0, 0, 0); BH(0, 0, 0, 1); BH(0, 0, 1, 0); BH(0, 0, 1, 1);
    AQ(0, 0, 1); AQ(0, 0, 3);
    asm volatile("s_waitcnt vmcnt(2)" ::: "memory");
    __builtin_amdgcn_s_barrier();

    for (int t = 0; t < NT; ++t) {
        const int sl = t & 1;
        const int ns = sl ^ 1;
        const char* sb = smem + sl * 65536;
        const bool pf = (t + 1 < NT);

#pragma unroll
        for (int p = 0; p < 4; ++p) {
            // ds_read this phase's A-frags (quarter wr*2 + (p>>1))
            bf16x8 af[2][2];
            const int aoff = abase + (p >> 1) * 8192 + (p & 1) * 4096;
            af[0][0] = *(const bf16x8*)(sb + aoff + swz0);
            af[0][1] = *(const bf16x8*)(sb + aoff + swz1);
            af[1][0] = *(const bf16x8*)(sb + aoff + 2048 + swz0);
            af[1][1] = *(const bf16x8*)(sb + aoff + 2048 + swz1);
            if (p == 0) {
#pragma unroll
                for (int jq = 0; jq < 4; ++jq) {
                    bfr[jq][0] = *(const bf16x8*)(sb + bbase + jq * 2048 + swz0);
                    bfr[jq][1] = *(const bf16x8*)(sb + bbase + jq * 2048 + swz1);
                }
            }
            // stage one region of tile t+1 into the dead slot
            if (pf) {
                if (p == 0)      { AQ(ns, t + 1, 0); AQ(ns, t + 1, 2); }
                else if (p == 1) { BH(ns, t + 1, 0, 0); BH(ns, t + 1, 0, 1);
                                   BH(ns, t + 1, 1, 0); BH(ns, t + 1, 1, 1); }
                else if (p == 2) { AQ(ns, t + 1, 1); AQ(ns, t + 1, 3); }
            }
            __builtin_amdgcn_s_barrier();
            asm volatile("s_waitcnt lgkmcnt(0)" ::: "memory");
            __builtin_amdgcn_sched_barrier(0);
            __builtin_amdgcn_s_setprio(1);
#pragma unroll
            for (int f = 0; f < 2; ++f)
#pragma unroll
                for (int jq = 0; jq < 4; ++jq) {
                    acc[2 * p + f][jq] = MFMA16(af[f][0], bfr[jq][0], acc[2 * p + f][jq]);
                    acc[2 * p + f][jq] = MFMA16(af[f][1], bfr[jq][1], acc[2 * p + f][jq]);
                }
            __builtin_amdgcn_s_setprio(0);
            if (p == 1) {
                if (pf) asm volatile("s_waitcnt vmcnt(6)" ::: "memory");
                else    asm volatile("s_waitcnt vmcnt(0)" ::: "memory");
            } else if (p == 3) {
                if (pf) asm volatile("s_waitcnt vmcnt(2)" ::: "memory");
                else    asm volatile("s_waitcnt vmcnt(0)" ::: "memory");
            }
            __builtin_amdgcn_s_barrier();
        }
    }
#undef AQ
#undef BH

    // epilogue: acc[i][j] -> row = m0 + wr*128 + (i>>1)*32 + (i&1)*16 +
    // quad*4 + r; col = n0 + wc*64 + j*16 + lrow.  V branch block-uniform.
    if (VtOut && n0 >= 2048) {
        const int bql = (m0 >> 11);
#pragma unroll
        for (int i = 0; i < 8; ++i) {
#pragma unroll
            for (int j = 0; j < 4; ++j) {
                const int col = n0 + wc * 64 + j * 16 + lrow;
                const float bsv = bias[col];
                const int vh = col - 2048;
                const int row = m0 + wr * 128 + (i >> 1) * 32 + (i & 1) * 16 + quad * 4;
                const int jj = row & (SEQ - 1);
                const int g = jj & 63;
                const int jj2 = (jj & ~63) | ((g >> 5) << 5)
                              | (((g >> 2) & 3) << 3) | (((g >> 4) & 1) << 2);
                bf16x4 vv;
#pragma unroll
                for (int r = 0; r < 4; ++r)
                    vv[r] = pack_bf16(acc[i][j][r] + bsv);
                *(bf16x4*)&VtOut[((size_t)bql * 16 * 64 + vh) * SEQ + jj2] = vv;
            }
        }
        return;
    }
#pragma unroll
    for (int i = 0; i < 8; ++i) {
#pragma unroll
        for (int j = 0; j < 4; ++j) {
            const int col = n0 + wc * 64 + j * 16 + lrow;
            const float bsv = bias[col];
#pragma unroll
            for (int r = 0; r < 4; ++r) {
                const int row = m0 + wr * 128 + (i >> 1) * 32 + (i & 1) * 16 + quad * 4 + r;
                Cb[(size_t)row * N + col] = pack_bf16(acc[i][j][r] + bsv);
            }
        }
    }
}

// ---------------------------------------------------------------------------
// gemm128 (gemm2, unchanged from r10-fixed): BM=BN=128, BK=64, 256 blocks,
// 64KB LDS -> 2 blocks/CU, 8 waves.  Counted gates per the r9 fix.
// ---------------------------------------------------------------------------
__global__ __launch_bounds__(512, 2) void gemm128(
    const bf16* __restrict__ A,    // M x K
    const bf16* __restrict__ Bw,   // N x K
    const float* __restrict__ bias,// N
    float* __restrict__ Cf,       // fp32 out
    int M, int N, int K)
{
    extern __shared__ char smem[];          // 2 x 32768 = 65536
    const int tid = threadIdx.x;
    const int lane = tid & 63;
    const int wave = tid >> 6;              // 0..7
    const int wr = wave >> 2;               // 0..1
    const int wc = wave & 3;                // 0..3 : cols [wc*32, +32)
    const int m0 = blockIdx.y * 128;
    const int n0 = blockIdx.x * 128;
    const int lrow = lane & 15;
    const int quad = lane >> 4;
    const int NT = K >> 6;

    const int l8 = lane >> 3;
    const int kx = ((lane & 7) ^ l8) << 3;  // inverse-swizzled source k offset

#define ASTG(sl, kt, c) do { \
    const int _gr = m0 + (c) * 64 + wave * 8 + l8; \
    gll16(A + (size_t)_gr * K + (size_t)(kt) * 64 + kx, \
          (bf16*)(smem + (sl) * 32768 + (c) * 8192 + wave * 1024)); \
} while (0)
#define BSTG(sl, kt, c) do { \
    const int _gc = n0 + (c) * 64 + wave * 8 + l8; \
    gll16(Bw + (size_t)_gc * K + (size_t)(kt) * 64 + kx, \
          (bf16*)(smem + (sl) * 32768 + 16384 + (c) * 8192 + wave * 1024)); \
} while (0)

    const int swz0 = ((quad ^ (lrow & 7)) << 4);
    const int swz1 = (((4 + quad) ^ (lrow & 7)) << 4);
    const int arow0 = (wr * 32 + lrow) * 128;   // ph0 base (region A0)
    const int brow = (wc * 32 + lrow) * 128;

    f32x4 acc[4][2] = {};
    bf16x8 bfr[2][2];   // [jq][ks], cached across the whole K-tile

    // prologue: stage tile 0 (B0,B1,A0,A1); leave A1 in flight.
    BSTG(0, 0, 0); BSTG(0, 0, 1);
    ASTG(0, 0, 0); ASTG(0, 0, 1);
    asm volatile("s_waitcnt vmcnt(1)" ::: "memory");
    __builtin_amdgcn_s_barrier();

    for (int t = 0; t < NT; ++t) {
        const int sl = t & 1;
        const int ns = sl ^ 1;
        const char* sb = smem + sl * 32768;
        const bool pf = (t + 1 < NT);

        // ---- phase 0: B (all) + A region 0 rows wr*32+{0,16}; stage B' ----
        if (pf) { BSTG(ns, t + 1, 0); BSTG(ns, t + 1, 1); }
        bf16x8 af[2][2];
#pragma unroll
        for (int jq = 0; jq < 2; ++jq) {
            bfr[jq][0] = *(const bf16x8*)(sb + 16384 + brow + jq * 2048 + swz0);
            bfr[jq][1] = *(const bf16x8*)(sb + 16384 + brow + jq * 2048 + swz1);
        }
#pragma unroll
        for (int iq = 0; iq < 2; ++iq) {
            af[iq][0] = *(const bf16x8*)(sb + arow0 + iq * 2048 + swz0);
            af[iq][1] = *(const bf16x8*)(sb + arow0 + iq * 2048 + swz1);
        }
        __builtin_amdgcn_s_setprio(1);
#pragma unroll
        for (int iq = 0; iq < 2; ++iq)
#pragma unroll
            for (int jq = 0; jq < 2; ++jq) {
                acc[iq][jq] = MFMA16(af[iq][0], bfr[jq][0], acc[iq][jq]);
                acc[iq][jq] = MFMA16(af[iq][1], bfr[jq][1], acc[iq][jq]);
            }
        __builtin_amdgcn_s_setprio(0);
        if (pf) asm volatile("s_waitcnt vmcnt(2)" ::: "memory");
        else    asm volatile("s_waitcnt vmcnt(0)" ::: "memory");
        __builtin_amdgcn_s_barrier();

        // ---- phase 1: A region 1 rows 64+wr*32+{0,16}; stage A' ----
        if (pf) { ASTG(ns, t + 1, 0); ASTG(ns, t + 1, 1); }
#pragma unroll
        for (int iq = 0; iq < 2; ++iq) {
            af[iq][0] = *(const bf16x8*)(sb + 8192 + arow0 + iq * 2048 + swz0);
            af[iq][1] = *(const bf16x8*)(sb + 8192 + arow0 + iq * 2048 + swz1);
        }
        __builtin_amdgcn_s_setprio(1);
#pragma unroll
        for (int iq = 0; iq < 2; ++iq)
#pragma unroll
            for (int jq = 0; jq < 2; ++jq) {
                acc[2 + iq][jq] = MFMA16(af[iq][0], bfr[jq][0], acc[2 + iq][jq]);
                acc[2 + iq][jq] = MFMA16(af[iq][1], bfr[jq][1], acc[2 + iq][jq]);
            }
        __builtin_amdgcn_s_setprio(0);
        if (pf) asm volatile("s_waitcnt vmcnt(1)" ::: "memory");
        else    asm volatile("s_waitcnt vmcnt(0)" ::: "memory");
        __builtin_amdgcn_s_barrier();
    }
#undef ASTG
#undef BSTG

    // epilogue: acc[iq][jq] -> row = m0 + (iq>>1)*64 + wr*32 + (iq&1)*16
    // + quad*4 + r;  col = n0 + wc*32 + jq*16 + lrow.
#pragma unroll
    for (int iq = 0; iq < 4; ++iq) {
#pragma unroll
        for (int jq = 0; jq < 2; ++jq) {
            const int col = n0 + wc * 32 + jq * 16 + lrow;
            const float bsv = bias[col];
#pragma unroll
            for (int r = 0; r < 4; ++r) {
                const int row = m0 + (iq >> 1) * 64 + wr * 32 + (iq & 1) * 16 + quad * 4 + r;
                Cf[(size_t)row * N + col] = acc[iq][jq][r] + bsv;
            }
        }
    }
}

// ---------------------------------------------------------------------------
// Flash attention v9 (best measured: 45.5 us, 52 VGPR): 8 waves = 4 qg x 2
// jp, T2 swizzle, setprio around MFMA clusters.
// ---------------------------------------------------------------------------
__global__ __launch_bounds__(512, 4) void attn_k(
    const bf16* __restrict__ QKV,  // M_TOK x 3072 : [Q | K | (unused V)]
    const bf16* __restrict__ Vt,   // [bh*64 + d][SEQ], j-permuted per 64-tile
    bf16* __restrict__ O)          // M_TOK x 1024
{
    const int bx = blockIdx.x;
    const int bh = (bx & 7) + 8 * ((bx >> 3) & 3);   // same bh -> same XCD (%8)
    const int qblk = bx >> 5;
    const int b = bh >> 4;
    const int h = bh & 15;
    const int lane = threadIdx.x & 63;
    const int wave = threadIdx.x >> 6;   // 0..7
    const int qg = wave & 3;             // q-group (32 rows each)
    const int jp = wave >> 2;            // j-chunk parity
    const int lrow = lane & 15;
    const int quad = lane >> 4;
    const int lk8 = quad * 8;

    __shared__ __align__(16) bf16 Ks[2][2][128 * 32];  // [stage][ksplit][j<128]
    __shared__ __align__(16) bf16 Vs[2][4][64 * 32];   // [stage][j-32-chunk][d<64]

    const size_t base = (size_t)b * SEQ * N_QKV;
    const bf16* Qp = QKV + base + h * HD;
    const bf16* Kp = QKV + base + FDIM + h * HD;
    const bf16* Vtp = Vt + (size_t)bh * HD * SEQ;

    const int qr0 = qblk * 128 + qg * 32;

    bf16x8 qf[2][2];
#pragma unroll
    for (int qt = 0; qt < 2; ++qt)
#pragma unroll
        for (int ks = 0; ks < 2; ++ks)
            qf[qt][ks] = *(const bf16x8*)(Qp + (size_t)(qr0 + qt * 16 + lrow) * N_QKV
                                          + ks * 32 + lk8);

    bf16x8 ones8;
#pragma unroll
    for (int e = 0; e < 8; ++e) ones8[e] = (bf16)1.0f;

    const f32x4 zf = {0.f, 0.f, 0.f, 0.f};

    f32x4 o[2][4] = {};
    f32x4 o4[2] = {};

    // staging: lane covers row base + (lane>>2); phys slot lane&3 stores
    // LOGICAL k-slot (lane&3)^((row>>1)&3) = (lane&3)^((lane>>3)&3).
    const int srow = wave * 16 + (lane >> 2);
    const int scol = ((lane & 3) ^ ((lane >> 3) & 3)) * 8;
    const bf16* kg = Kp + (size_t)srow * N_QKV + scol;
    const int vsrow = qg * 16 + (lane >> 2);
    const bf16* vg = Vtp + (size_t)vsrow * SEQ + jp * 32 + scol;
    const int kwo = wave * 512;
    // read: logical chunk `quad` of row (16*n + lrow) is at phys slot
    // quad ^ ((lrow>>1)&3).
    const int swz8 = (quad ^ ((lrow >> 1) & 3)) * 8;

    gll16(kg,      &Ks[0][0][0] + kwo);
    gll16(kg + 32, &Ks[0][1][0] + kwo);
    gll16(vg,      &Vs[0][0][0] + kwo);
    gll16(vg + 64, &Vs[0][2][0] + kwo);
    kg += (size_t)128 * N_QKV;
    vg += 128;

    for (int jt = 0; jt < SEQ / 128; ++jt) {
        const int cur = jt & 1;
        __syncthreads();

        if (jt + 1 < SEQ / 128) {
            const int nxt = cur ^ 1;
            gll16(kg,      &Ks[nxt][0][0] + kwo);
            gll16(kg + 32, &Ks[nxt][1][0] + kwo);
            gll16(vg,      &Vs[nxt][0][0] + kwo);
            gll16(vg + 64, &Vs[nxt][2][0] + kwo);
            kg += (size_t)128 * N_QKV;
            vg += 128;
        }

#pragma unroll
        for (int pp = 0; pp < 2; ++pp) {
            const int p = (pp << 1) | jp;
            f32x4 Sp[2][2];
            __builtin_amdgcn_s_setprio(1);
#pragma unroll
            for (int m = 0; m < 2; ++m) {
                const int jn = 2 * p + m;
                bf16x8 kb0 = *(const bf16x8*)&Ks[cur][0][(jn * 16 + lrow) * 32 + swz8];
                bf16x8 kb1 = *(const bf16x8*)&Ks[cur][1][(jn * 16 + lrow) * 32 + swz8];
                Sp[m][0] = MFMA16(kb0, qf[0][0], zf);
                Sp[m][0] = MFMA16(kb1, qf[0][1], Sp[m][0]);
                Sp[m][1] = MFMA16(kb0, qf[1][0], zf);
                Sp[m][1] = MFMA16(kb1, qf[1][1], Sp[m][1]);
            }
            __builtin_amdgcn_s_setprio(0);

            union { bf16x8 v; uint32_t d[4]; } pb[2];
#pragma unroll
            for (int qt = 0; qt < 2; ++qt) {
                const f32x4 s0 = Sp[0][qt];
                const f32x4 s1 = Sp[1][qt];
                pb[qt].d[0] = pk2(__builtin_amdgcn_exp2f(s0[0]),
                                  __builtin_amdgcn_exp2f(s0[1]));
                pb[qt].d[1] = pk2(__builtin_amdgcn_exp2f(s0[2]),
                                  __builtin_amdgcn_exp2f(s0[3]));
                pb[qt].d[2] = pk2(__builtin_amdgcn_exp2f(s1[0]),
                                  __builtin_amdgcn_exp2f(s1[1]));
                pb[qt].d[3] = pk2(__builtin_amdgcn_exp2f(s1[2]),
                                  __builtin_amdgcn_exp2f(s1[3]));
            }

            __builtin_amdgcn_s_setprio(1);
            o4[0] = MFMA16(ones8, pb[0].v, o4[0]);
            o4[1] = MFMA16(ones8, pb[1].v, o4[1]);
#pragma unroll
            for (int df = 0; df < 4; ++df) {
                bf16x8 vA = *(const bf16x8*)&Vs[cur][p][(df * 16 + lrow) * 32 + swz8];
                o[0][df] = MFMA16(vA, pb[0].v, o[0][df]);
                o[1][df] = MFMA16(vA, pb[1].v, o[1][df]);
            }
            __builtin_amdgcn_s_setprio(0);
        }
    }

    // combine j-parity partials through LDS (safe to overwrite Ks/Vs now)
    __syncthreads();
    float* shO = (float*)Ks;
    float* shS = (float*)Vs;
    if (jp == 1) {
#pragma unroll
        for (int qt = 0; qt < 2; ++qt)
#pragma unroll
            for (int df = 0; df < 4; ++df)
                *(f32x4*)&shO[((((qt * 4 + df) * 4) + qg) * 64 + lane) * 4] = o[qt][df];
        shS[(qg * 64 + lane) * 2 + 0] = o4[0][0];
        shS[(qg * 64 + lane) * 2 + 1] = o4[1][0];
    }
    __syncthreads();
    if (jp == 1) return;

#pragma unroll
    for (int qt = 0; qt < 2; ++qt)
#pragma unroll
        for (int df = 0; df < 4; ++df) {
            f32x4 t = *(const f32x4*)&shO[((((qt * 4 + df) * 4) + qg) * 64 + lane) * 4];
            o[qt][df][0] += t[0]; o[qt][df][1] += t[1];
            o[qt][df][2] += t[2]; o[qt][df][3] += t[3];
        }
    const float den0 = o4[0][0] + shS[(qg * 64 + lane) * 2 + 0];
    const float den1 = o4[1][0] + shS[(qg * 64 + lane) * 2 + 1];

#pragma unroll
    for (int qt = 0; qt < 2; ++qt) {
        const float inv = 1.0f / (qt ? den1 : den0);
        const int q = qr0 + qt * 16 + lrow;
#pragma unroll
        for (int df = 0; df < 4; ++df) {
            bf16x4 vv;
#pragma unroll
            for (int r = 0; r < 4; ++r)
                vv[r] = pack_bf16(o[qt][df][r] * inv);
            *(bf16x4*)&O[(size_t)(b * SEQ + q) * FDIM + h * HD + df * 16 + quad * 4] = vv;
        }
    }
}

// ---------------------------------------------------------------------------
extern "C" void kernel_launch(void* const* d_in, const int* in_sizes, int n_in,
                              void* d_out, int out_size, void* d_ws, size_t ws_size,
                              hipStream_t stream) {
    (void)in_sizes; (void)n_in; (void)out_size; (void)ws_size;
    const float* x  = (const float*)d_in[0];
    const float* Wq = (const float*)d_in[1];
    const float* bq = (const float*)d_in[2];
    const float* Wk = (const float*)d_in[3];
    const float* bk = (const float*)d_in[4];
    const float* Wv = (const float*)d_in[5];
    const float* bv = (const float*)d_in[6];
    const float* Wo = (const float*)d_in[7];
    const float* bo = (const float*)d_in[8];
    float* out = (float*)d_out;

    char* ws = (char*)d_ws;
    bf16* xb    = (bf16*)(ws);                // 8 MB; reused as Ob after GEMM1
    bf16* Wcat  = (bf16*)(ws + 8388608);      // 6 MB
    bf16* Wob   = (bf16*)(ws + 14680064);     // 2 MB
    float* bcat = (float*)(ws + 16777216);    // 12 KB
    bf16* QKV   = (bf16*)(ws + 16789504);     // 24 MB (V third unused)
    bf16* Vt    = (bf16*)(ws + 41955328);     // 8 MB, j-permuted layout
    bf16* Ob    = xb;                         // x no longer needed after GEMM1

    static bool s_attr_done = false;
    if (!s_attr_done) {
        (void)hipFuncSetAttribute(reinterpret_cast<const void*>(gemm_qkv),
                                  hipFuncAttributeMaxDynamicSharedMemorySize,
                                  131072);
        (void)hipFuncSetAttribute(reinterpret_cast<const void*>(gemm128),
                                  hipFuncAttributeMaxDynamicSharedMemorySize,
                                  65536);
        s_attr_done = true;
    }

    convert_k<<<dim3(1024), dim3(256), 0, stream>>>(x, Wq, bq, Wk, bk, Wv, bv, Wo,
                                                    xb, Wcat, Wob, bcat);
    gemm_qkv<<<dim3((N_QKV / 256) * (M_TOK / 256)), dim3(512), 131072, stream>>>(
        xb, Wcat, bcat, QKV, Vt, M_TOK, N_QKV, FDIM);
    attn_k<<<dim3((SEQ / 128) * BB * NH), dim3(512), 0, stream>>>(QKV, Vt, Ob);
    gemm128<<<dim3(FDIM / 128, M_TOK / 128), dim3(512), 65536, stream>>>(
        Ob, Wob, bo, out, M_TOK, FDIM, FDIM);
}

// Round 13
// 180.385 us; speedup vs baseline: 1.0136x; 1.0136x over previous
//
#include <hip/hip_runtime.h>
#include <hip/hip_bf16.h>
#include <stdint.h>
#include <stddef.h>

typedef __bf16 bf16;
typedef __attribute__((ext_vector_type(8))) __bf16 bf16x8;
typedef __attribute__((ext_vector_type(4))) __bf16 bf16x4;
typedef __attribute__((ext_vector_type(2))) __bf16 bf16x2;
typedef __attribute__((ext_vector_type(4))) float f32x4;

#define MFMA16(a, b, c) __builtin_amdgcn_mfma_f32_16x16x32_bf16(a, b, c, 0, 0, 0)

#define BB 2
#define SEQ 2048
#define FDIM 1024
#define NH 16
#define HD 64
#define M_TOK 4096   /* BB*SEQ */
#define N_QKV 3072   /* 3*FDIM */

#define CSC 0.04508422f  /* (1/32) * log2(e) — folded into Wq/bq */

// async global->LDS, 16B per lane; LDS dest is wave-uniform base + lane*16
__device__ __forceinline__ void gll16(const bf16* g, bf16* l) {
    __builtin_amdgcn_global_load_lds(
        (const __attribute__((address_space(1))) void*)g,
        (__attribute__((address_space(3))) void*)l, 16, 0, 0);
}

// fast f32 -> bf16 (round-to-nearest; 2 VALU ops)
__device__ __forceinline__ bf16 pack_bf16(float f) {
    uint32_t u = __builtin_bit_cast(uint32_t, f);
    uint16_t h = (uint16_t)((u + 0x8000u) >> 16);
    return __builtin_bit_cast(bf16, h);
}

// pack two f32 -> one dword of two bf16 (lo=a, hi=b)
__device__ __forceinline__ uint32_t pk2(float a, float b) {
#if __has_builtin(__builtin_amdgcn_cvt_pk_bf16_f32)
    bf16x2 t = __builtin_amdgcn_cvt_pk_bf16_f32(a, b);
    return __builtin_bit_cast(uint32_t, t);
#else
    uint32_t ua = __builtin_bit_cast(uint32_t, a) + 0x8000u;
    uint32_t ub = __builtin_bit_cast(uint32_t, b) + 0x8000u;
    return __builtin_amdgcn_perm(ub, ua, 0x07060302);
#endif
}

// ---------------------------------------------------------------------------
// fp32 -> bf16 conversion; Wq/bq pre-scaled by CSC.
// ---------------------------------------------------------------------------
__global__ __launch_bounds__(256) void convert_k(
    const float* __restrict__ x,
    const float* __restrict__ Wq, const float* __restrict__ bq,
    const float* __restrict__ Wk, const float* __restrict__ bk,
    const float* __restrict__ Wv, const float* __restrict__ bv,
    const float* __restrict__ Wo,
    bf16* __restrict__ xb, bf16* __restrict__ Wcat, bf16* __restrict__ Wob,
    float* __restrict__ bcat)
{
    const int tid = blockIdx.x * blockDim.x + threadIdx.x;
    const int nt = gridDim.x * blockDim.x;
    const int NX4 = M_TOK * FDIM / 4;
    const int NW4 = FDIM * FDIM / 4;

    for (int i = tid; i < NX4; i += nt) {
        float4 v = ((const float4*)x)[i];
        bf16x4 o; o[0] = (bf16)v.x; o[1] = (bf16)v.y; o[2] = (bf16)v.z; o[3] = (bf16)v.w;
        ((bf16x4*)xb)[i] = o;
    }
    for (int i = tid; i < NW4; i += nt) {
        float4 v = ((const float4*)Wq)[i];
        bf16x4 o;
        o[0] = (bf16)(v.x * CSC); o[1] = (bf16)(v.y * CSC);
        o[2] = (bf16)(v.z * CSC); o[3] = (bf16)(v.w * CSC);
        ((bf16x4*)Wcat)[i] = o;
        v = ((const float4*)Wk)[i];
        o[0] = (bf16)v.x; o[1] = (bf16)v.y; o[2] = (bf16)v.z; o[3] = (bf16)v.w;
        ((bf16x4*)Wcat)[NW4 + i] = o;
        v = ((const float4*)Wv)[i];
        o[0] = (bf16)v.x; o[1] = (bf16)v.y; o[2] = (bf16)v.z; o[3] = (bf16)v.w;
        ((bf16x4*)Wcat)[2 * NW4 + i] = o;
        v = ((const float4*)Wo)[i];
        o[0] = (bf16)v.x; o[1] = (bf16)v.y; o[2] = (bf16)v.z; o[3] = (bf16)v.w;
        ((bf16x4*)Wob)[i] = o;
    }
    for (int i = tid; i < FDIM; i += nt) {
        bcat[i] = bq[i] * CSC;
        bcat[FDIM + i] = bk[i];
        bcat[2 * FDIM + i] = bv[i];
    }
}

// ---------------------------------------------------------------------------
// gemm192 (QKV projection, r11 best-measured): BM=256, BN=192, BK=64 ->
// grid 16x16 = 256 blocks (full CU coverage).  LDS 2 x 56KB = 112 KB ->
// 1 block/CU, 2 waves/SIMD.  8 waves = 4(row) x 2(col-band of 96).
// 2 phases/K-tile (row-region trick): phase mh covers A-pair [mh*128,+128);
// wave rows mh*128 + wr*32 + {0,16}.  B cached in regs across both phases.
// Stage order: ph0: B0,B1,B2,A0,A1 | ph1: A2,A3.  Gates: end-ph0 vmcnt(5),
// end-ph1 vmcnt(2) (traced r10).  T2 swizzle, T5 setprio.
// Epilogue: per-column V branch (BN=192 straddles the 2048 boundary).
// ---------------------------------------------------------------------------
__global__ __launch_bounds__(512, 2) void gemm192(
    const bf16* __restrict__ A,    // M x K
    const bf16* __restrict__ Bw,   // N x K
    const float* __restrict__ bias,// N
    bf16* __restrict__ Cb,         // bf16 out
    bf16* __restrict__ VtOut,      // transposed-V output (cols >= 2048)
    int M, int N, int K)
{
    extern __shared__ char smem[];          // 2 x 57344 = 114688
    const int tid = threadIdx.x;
    const int lane = tid & 63;
    const int wave = tid >> 6;              // 0..7
    const int wr = wave >> 1;               // 0..3
    const int wcn = wave & 1;               // 0..1 : cols [wcn*96, +96)
    const int m0 = blockIdx.y * 256;
    const int n0 = blockIdx.x * 192;
    const int lrow = lane & 15;
    const int quad = lane >> 4;
    const int NT = K >> 6;

    const int l8 = lane >> 3;
    const int kx = ((lane & 7) ^ l8) << 3;  // inverse-swizzled source k offset

#define ASTG(sl, kt, c) do { \
    const int _gr = m0 + (c) * 64 + wave * 8 + l8; \
    gll16(A + (size_t)_gr * K + (size_t)(kt) * 64 + kx, \
          (bf16*)(smem + (sl) * 57344 + (c) * 8192 + wave * 1024)); \
} while (0)
#define BSTG(sl, kt, c) do { \
    const int _gc = n0 + (c) * 64 + wave * 8 + l8; \
    gll16(Bw + (size_t)_gc * K + (size_t)(kt) * 64 + kx, \
          (bf16*)(smem + (sl) * 57344 + 32768 + (c) * 8192 + wave * 1024)); \
} while (0)

    const int swz0 = ((quad ^ (lrow & 7)) << 4);
    const int swz1 = (((4 + quad) ^ (lrow & 7)) << 4);
    const int arow0 = (wr * 32 + lrow) * 128;       // within a region pair
    const int brow = (wcn * 96 + lrow) * 128;

    f32x4 acc[2][2][6] = {};    // [mh][f][jf]
    bf16x8 bfr[6][2];           // [jf][ks], cached across both phases

    // prologue: stage tile 0 (B0,B1,B2,A0,A1,A2,A3); leave A2,A3 in flight.
    BSTG(0, 0, 0); BSTG(0, 0, 1); BSTG(0, 0, 2);
    ASTG(0, 0, 0); ASTG(0, 0, 1);
    ASTG(0, 0, 2); ASTG(0, 0, 3);
    asm volatile("s_waitcnt vmcnt(2)" ::: "memory");
    __builtin_amdgcn_s_barrier();

    for (int t = 0; t < NT; ++t) {
        const int sl = t & 1;
        const int ns = sl ^ 1;
        const char* sb = smem + sl * 57344;
        const bool pf = (t + 1 < NT);

        // ---- phase 0: B all + A pair 0 (rows wr*32+{0,16}) ----
        if (pf) {
            BSTG(ns, t + 1, 0); BSTG(ns, t + 1, 1); BSTG(ns, t + 1, 2);
            ASTG(ns, t + 1, 0); ASTG(ns, t + 1, 1);
        }
        bf16x8 af[2][2];
#pragma unroll
        for (int jf = 0; jf < 6; ++jf) {
            bfr[jf][0] = *(const bf16x8*)(sb + 32768 + brow + jf * 2048 + swz0);
            bfr[jf][1] = *(const bf16x8*)(sb + 32768 + brow + jf * 2048 + swz1);
        }
#pragma unroll
        for (int f = 0; f < 2; ++f) {
            af[f][0] = *(const bf16x8*)(sb + arow0 + f * 2048 + swz0);
            af[f][1] = *(const bf16x8*)(sb + arow0 + f * 2048 + swz1);
        }
        __builtin_amdgcn_s_setprio(1);
#pragma unroll
        for (int f = 0; f < 2; ++f)
#pragma unroll
            for (int jf = 0; jf < 6; ++jf) {
                acc[0][f][jf] = MFMA16(af[f][0], bfr[jf][0], acc[0][f][jf]);
                acc[0][f][jf] = MFMA16(af[f][1], bfr[jf][1], acc[0][f][jf]);
            }
        __builtin_amdgcn_s_setprio(0);
        if (pf) asm volatile("s_waitcnt vmcnt(5)" ::: "memory");
        else    asm volatile("s_waitcnt vmcnt(0)" ::: "memory");
        __builtin_amdgcn_s_barrier();

        // ---- phase 1: A pair 1 (rows 128 + wr*32+{0,16}) ----
        if (pf) { ASTG(ns, t + 1, 2); ASTG(ns, t + 1, 3); }
#pragma unroll
        for (int f = 0; f < 2; ++f) {
            af[f][0] = *(const bf16x8*)(sb + 16384 + arow0 + f * 2048 + swz0);
            af[f][1] = *(const bf16x8*)(sb + 16384 + arow0 + f * 2048 + swz1);
        }
        __builtin_amdgcn_s_setprio(1);
#pragma unroll
        for (int f = 0; f < 2; ++f)
#pragma unroll
            for (int jf = 0; jf < 6; ++jf) {
                acc[1][f][jf] = MFMA16(af[f][0], bfr[jf][0], acc[1][f][jf]);
                acc[1][f][jf] = MFMA16(af[f][1], bfr[jf][1], acc[1][f][jf]);
            }
        __builtin_amdgcn_s_setprio(0);
        if (pf) asm volatile("s_waitcnt vmcnt(2)" ::: "memory");
        else    asm volatile("s_waitcnt vmcnt(0)" ::: "memory");
        __builtin_amdgcn_s_barrier();
    }
#undef ASTG
#undef BSTG

    // epilogue: row = m0 + mh*128 + wr*32 + f*16 + quad*4 + r;
    // col = n0 + wcn*96 + jf*16 + lrow.  Per-column V branch.
    const int bql = (m0 >> 11);
#pragma unroll
    for (int mh = 0; mh < 2; ++mh) {
#pragma unroll
        for (int f = 0; f < 2; ++f) {
#pragma unroll
            for (int jf = 0; jf < 6; ++jf) {
                const int col = n0 + wcn * 96 + jf * 16 + lrow;
                const float bsv = bias[col];
                const int row = m0 + mh * 128 + wr * 32 + f * 16 + quad * 4;
                if (VtOut && col >= 2048) {
                    const int vh = col - 2048;              // h*64 + d
                    const int jj = row & (SEQ - 1);
                    const int g = jj & 63;
                    const int jj2 = (jj & ~63) | ((g >> 5) << 5)
                                  | (((g >> 2) & 3) << 3) | (((g >> 4) & 1) << 2);
                    bf16x4 vv;
#pragma unroll
                    for (int r = 0; r < 4; ++r)
                        vv[r] = pack_bf16(acc[mh][f][jf][r] + bsv);
                    *(bf16x4*)&VtOut[((size_t)bql * 16 * 64 + vh) * SEQ + jj2] = vv;
                } else {
#pragma unroll
                    for (int r = 0; r < 4; ++r)
                        Cb[(size_t)(row + r) * N + col] =
                            pack_bf16(acc[mh][f][jf][r] + bsv);
                }
            }
        }
    }
}

// ---------------------------------------------------------------------------
// gemm128 (gemm2, r10-fixed): BM=BN=128, BK=64, 256 blocks, 64KB LDS ->
// 2 blocks/CU, 8 waves.  Row-region phases + counted gates (r9 trace).
// ---------------------------------------------------------------------------
__global__ __launch_bounds__(512, 2) void gemm128(
    const bf16* __restrict__ A,    // M x K
    const bf16* __restrict__ Bw,   // N x K
    const float* __restrict__ bias,// N
    float* __restrict__ Cf,       // fp32 out
    int M, int N, int K)
{
    extern __shared__ char smem[];          // 2 x 32768 = 65536
    const int tid = threadIdx.x;
    const int lane = tid & 63;
    const int wave = tid >> 6;              // 0..7
    const int wr = wave >> 2;               // 0..1
    const int wc = wave & 3;                // 0..3 : cols [wc*32, +32)
    const int m0 = blockIdx.y * 128;
    const int n0 = blockIdx.x * 128;
    const int lrow = lane & 15;
    const int quad = lane >> 4;
    const int NT = K >> 6;

    const int l8 = lane >> 3;
    const int kx = ((lane & 7) ^ l8) << 3;  // inverse-swizzled source k offset

#define ASTG(sl, kt, c) do { \
    const int _gr = m0 + (c) * 64 + wave * 8 + l8; \
    gll16(A + (size_t)_gr * K + (size_t)(kt) * 64 + kx, \
          (bf16*)(smem + (sl) * 32768 + (c) * 8192 + wave * 1024)); \
} while (0)
#define BSTG(sl, kt, c) do { \
    const int _gc = n0 + (c) * 64 + wave * 8 + l8; \
    gll16(Bw + (size_t)_gc * K + (size_t)(kt) * 64 + kx, \
          (bf16*)(smem + (sl) * 32768 + 16384 + (c) * 8192 + wave * 1024)); \
} while (0)

    const int swz0 = ((quad ^ (lrow & 7)) << 4);
    const int swz1 = (((4 + quad) ^ (lrow & 7)) << 4);
    const int arow0 = (wr * 32 + lrow) * 128;   // ph0 base (region A0)
    const int brow = (wc * 32 + lrow) * 128;

    f32x4 acc[4][2] = {};
    bf16x8 bfr[2][2];   // [jq][ks], cached across the whole K-tile

    // prologue: stage tile 0 (B0,B1,A0,A1); leave A1 in flight.
    BSTG(0, 0, 0); BSTG(0, 0, 1);
    ASTG(0, 0, 0); ASTG(0, 0, 1);
    asm volatile("s_waitcnt vmcnt(1)" ::: "memory");
    __builtin_amdgcn_s_barrier();

    for (int t = 0; t < NT; ++t) {
        const int sl = t & 1;
        const int ns = sl ^ 1;
        const char* sb = smem + sl * 32768;
        const bool pf = (t + 1 < NT);

        // ---- phase 0: B (all) + A region 0 rows wr*32+{0,16}; stage B' ----
        if (pf) { BSTG(ns, t + 1, 0); BSTG(ns, t + 1, 1); }
        bf16x8 af[2][2];
#pragma unroll
        for (int jq = 0; jq < 2; ++jq) {
            bfr[jq][0] = *(const bf16x8*)(sb + 16384 + brow + jq * 2048 + swz0);
            bfr[jq][1] = *(const bf16x8*)(sb + 16384 + brow + jq * 2048 + swz1);
        }
#pragma unroll
        for (int iq = 0; iq < 2; ++iq) {
            af[iq][0] = *(const bf16x8*)(sb + arow0 + iq * 2048 + swz0);
            af[iq][1] = *(const bf16x8*)(sb + arow0 + iq * 2048 + swz1);
        }
        __builtin_amdgcn_s_setprio(1);
#pragma unroll
        for (int iq = 0; iq < 2; ++iq)
#pragma unroll
            for (int jq = 0; jq < 2; ++jq) {
                acc[iq][jq] = MFMA16(af[iq][0], bfr[jq][0], acc[iq][jq]);
                acc[iq][jq] = MFMA16(af[iq][1], bfr[jq][1], acc[iq][jq]);
            }
        __builtin_amdgcn_s_setprio(0);
        if (pf) asm volatile("s_waitcnt vmcnt(2)" ::: "memory");
        else    asm volatile("s_waitcnt vmcnt(0)" ::: "memory");
        __builtin_amdgcn_s_barrier();

        // ---- phase 1: A region 1 rows 64+wr*32+{0,16}; stage A' ----
        if (pf) { ASTG(ns, t + 1, 0); ASTG(ns, t + 1, 1); }
#pragma unroll
        for (int iq = 0; iq < 2; ++iq) {
            af[iq][0] = *(const bf16x8*)(sb + 8192 + arow0 + iq * 2048 + swz0);
            af[iq][1] = *(const bf16x8*)(sb + 8192 + arow0 + iq * 2048 + swz1);
        }
        __builtin_amdgcn_s_setprio(1);
#pragma unroll
        for (int iq = 0; iq < 2; ++iq)
#pragma unroll
            for (int jq = 0; jq < 2; ++jq) {
                acc[2 + iq][jq] = MFMA16(af[iq][0], bfr[jq][0], acc[2 + iq][jq]);
                acc[2 + iq][jq] = MFMA16(af[iq][1], bfr[jq][1], acc[2 + iq][jq]);
            }
        __builtin_amdgcn_s_setprio(0);
        if (pf) asm volatile("s_waitcnt vmcnt(1)" ::: "memory");
        else    asm volatile("s_waitcnt vmcnt(0)" ::: "memory");
        __builtin_amdgcn_s_barrier();
    }
#undef ASTG
#undef BSTG

    // epilogue: acc[iq][jq] -> row = m0 + (iq>>1)*64 + wr*32 + (iq&1)*16
    // + quad*4 + r;  col = n0 + wc*32 + jq*16 + lrow.
#pragma unroll
    for (int iq = 0; iq < 4; ++iq) {
#pragma unroll
        for (int jq = 0; jq < 2; ++jq) {
            const int col = n0 + wc * 32 + jq * 16 + lrow;
            const float bsv = bias[col];
#pragma unroll
            for (int r = 0; r < 4; ++r) {
                const int row = m0 + (iq >> 1) * 64 + wr * 32 + (iq & 1) * 16 + quad * 4 + r;
                Cf[(size_t)row * N + col] = acc[iq][jq][r] + bsv;
            }
        }
    }
}

// ---------------------------------------------------------------------------
// Flash attention v9 (best measured: 45.4 us, 52 VGPR): 8 waves = 4 qg x 2
// jp, T2 swizzle, setprio around MFMA clusters.  Pipe balance: LDS ~45%,
// VALU ~41%, MFMA ~33% — further restructure (2qg x 4jp) exceeds the
// 128-VGPR budget at 4 waves/SIMD (spill).  Kept as-is.
// ---------------------------------------------------------------------------
__global__ __launch_bounds__(512, 4) void attn_k(
    const bf16* __restrict__ QKV,  // M_TOK x 3072 : [Q | K | (unused V)]
    const bf16* __restrict__ Vt,   // [bh*64 + d][SEQ], j-permuted per 64-tile
    bf16* __restrict__ O)          // M_TOK x 1024
{
    const int bx = blockIdx.x;
    const int bh = (bx & 7) + 8 * ((bx >> 3) & 3);   // same bh -> same XCD (%8)
    const int qblk = bx >> 5;
    const int b = bh >> 4;
    const int h = bh & 15;
    const int lane = threadIdx.x & 63;
    const int wave = threadIdx.x >> 6;   // 0..7
    const int qg = wave & 3;             // q-group (32 rows each)
    const int jp = wave >> 2;            // j-chunk parity
    const int lrow = lane & 15;
    const int quad = lane >> 4;
    const int lk8 = quad * 8;

    __shared__ __align__(16) bf16 Ks[2][2][128 * 32];  // [stage][ksplit][j<128]
    __shared__ __align__(16) bf16 Vs[2][4][64 * 32];   // [stage][j-32-chunk][d<64]

    const size_t base = (size_t)b * SEQ * N_QKV;
    const bf16* Qp = QKV + base + h * HD;
    const bf16* Kp = QKV + base + FDIM + h * HD;
    const bf16* Vtp = Vt + (size_t)bh * HD * SEQ;

    const int qr0 = qblk * 128 + qg * 32;

    bf16x8 qf[2][2];
#pragma unroll
    for (int qt = 0; qt < 2; ++qt)
#pragma unroll
        for (int ks = 0; ks < 2; ++ks)
            qf[qt][ks] = *(const bf16x8*)(Qp + (size_t)(qr0 + qt * 16 + lrow) * N_QKV
                                          + ks * 32 + lk8);

    bf16x8 ones8;
#pragma unroll
    for (int e = 0; e < 8; ++e) ones8[e] = (bf16)1.0f;

    const f32x4 zf = {0.f, 0.f, 0.f, 0.f};

    f32x4 o[2][4] = {};
    f32x4 o4[2] = {};

    // staging: lane covers row base + (lane>>2); phys slot lane&3 stores
    // LOGICAL k-slot (lane&3)^((row>>1)&3) = (lane&3)^((lane>>3)&3).
    const int srow = wave * 16 + (lane >> 2);
    const int scol = ((lane & 3) ^ ((lane >> 3) & 3)) * 8;
    const bf16* kg = Kp + (size_t)srow * N_QKV + scol;
    const int vsrow = qg * 16 + (lane >> 2);
    const bf16* vg = Vtp + (size_t)vsrow * SEQ + jp * 32 + scol;
    const int kwo = wave * 512;
    // read: logical chunk `quad` of row (16*n + lrow) is at phys slot
    // quad ^ ((lrow>>1)&3).
    const int swz8 = (quad ^ ((lrow >> 1) & 3)) * 8;

    gll16(kg,      &Ks[0][0][0] + kwo);
    gll16(kg + 32, &Ks[0][1][0] + kwo);
    gll16(vg,      &Vs[0][0][0] + kwo);
    gll16(vg + 64, &Vs[0][2][0] + kwo);
    kg += (size_t)128 * N_QKV;
    vg += 128;

    for (int jt = 0; jt < SEQ / 128; ++jt) {
        const int cur = jt & 1;
        __syncthreads();

        if (jt + 1 < SEQ / 128) {
            const int nxt = cur ^ 1;
            gll16(kg,      &Ks[nxt][0][0] + kwo);
            gll16(kg + 32, &Ks[nxt][1][0] + kwo);
            gll16(vg,      &Vs[nxt][0][0] + kwo);
            gll16(vg + 64, &Vs[nxt][2][0] + kwo);
            kg += (size_t)128 * N_QKV;
            vg += 128;
        }

#pragma unroll
        for (int pp = 0; pp < 2; ++pp) {
            const int p = (pp << 1) | jp;
            f32x4 Sp[2][2];
            __builtin_amdgcn_s_setprio(1);
#pragma unroll
            for (int m = 0; m < 2; ++m) {
                const int jn = 2 * p + m;
                bf16x8 kb0 = *(const bf16x8*)&Ks[cur][0][(jn * 16 + lrow) * 32 + swz8];
                bf16x8 kb1 = *(const bf16x8*)&Ks[cur][1][(jn * 16 + lrow) * 32 + swz8];
                Sp[m][0] = MFMA16(kb0, qf[0][0], zf);
                Sp[m][0] = MFMA16(kb1, qf[0][1], Sp[m][0]);
                Sp[m][1] = MFMA16(kb0, qf[1][0], zf);
                Sp[m][1] = MFMA16(kb1, qf[1][1], Sp[m][1]);
            }
            __builtin_amdgcn_s_setprio(0);

            union { bf16x8 v; uint32_t d[4]; } pb[2];
#pragma unroll
            for (int qt = 0; qt < 2; ++qt) {
                const f32x4 s0 = Sp[0][qt];
                const f32x4 s1 = Sp[1][qt];
                pb[qt].d[0] = pk2(__builtin_amdgcn_exp2f(s0[0]),
                                  __builtin_amdgcn_exp2f(s0[1]));
                pb[qt].d[1] = pk2(__builtin_amdgcn_exp2f(s0[2]),
                                  __builtin_amdgcn_exp2f(s0[3]));
                pb[qt].d[2] = pk2(__builtin_amdgcn_exp2f(s1[0]),
                                  __builtin_amdgcn_exp2f(s1[1]));
                pb[qt].d[3] = pk2(__builtin_amdgcn_exp2f(s1[2]),
                                  __builtin_amdgcn_exp2f(s1[3]));
            }

            __builtin_amdgcn_s_setprio(1);
            o4[0] = MFMA16(ones8, pb[0].v, o4[0]);
            o4[1] = MFMA16(ones8, pb[1].v, o4[1]);
#pragma unroll
            for (int df = 0; df < 4; ++df) {
                bf16x8 vA = *(const bf16x8*)&Vs[cur][p][(df * 16 + lrow) * 32 + swz8];
                o[0][df] = MFMA16(vA, pb[0].v, o[0][df]);
                o[1][df] = MFMA16(vA, pb[1].v, o[1][df]);
            }
            __builtin_amdgcn_s_setprio(0);
        }
    }

    // combine j-parity partials through LDS (safe to overwrite Ks/Vs now)
    __syncthreads();
    float* shO = (float*)Ks;
    float* shS = (float*)Vs;
    if (jp == 1) {
#pragma unroll
        for (int qt = 0; qt < 2; ++qt)
#pragma unroll
            for (int df = 0; df < 4; ++df)
                *(f32x4*)&shO[((((qt * 4 + df) * 4) + qg) * 64 + lane) * 4] = o[qt][df];
        shS[(qg * 64 + lane) * 2 + 0] = o4[0][0];
        shS[(qg * 64 + lane) * 2 + 1] = o4[1][0];
    }
    __syncthreads();
    if (jp == 1) return;

#pragma unroll
    for (int qt = 0; qt < 2; ++qt)
#pragma unroll
        for (int df = 0; df < 4; ++df) {
            f32x4 t = *(const f32x4*)&shO[((((qt * 4 + df) * 4) + qg) * 64 + lane) * 4];
            o[qt][df][0] += t[0]; o[qt][df][1] += t[1];
            o[qt][df][2] += t[2]; o[qt][df][3] += t[3];
        }
    const float den0 = o4[0][0] + shS[(qg * 64 + lane) * 2 + 0];
    const float den1 = o4[1][0] + shS[(qg * 64 + lane) * 2 + 1];

#pragma unroll
    for (int qt = 0; qt < 2; ++qt) {
        const float inv = 1.0f / (qt ? den1 : den0);
        const int q = qr0 + qt * 16 + lrow;
#pragma unroll
        for (int df = 0; df < 4; ++df) {
            bf16x4 vv;
#pragma unroll
            for (int r = 0; r < 4; ++r)
                vv[r] = pack_bf16(o[qt][df][r] * inv);
            *(bf16x4*)&O[(size_t)(b * SEQ + q) * FDIM + h * HD + df * 16 + quad * 4] = vv;
        }
    }
}

// ---------------------------------------------------------------------------
extern "C" void kernel_launch(void* const* d_in, const int* in_sizes, int n_in,
                              void* d_out, int out_size, void* d_ws, size_t ws_size,
                              hipStream_t stream) {
    (void)in_sizes; (void)n_in; (void)out_size; (void)ws_size;
    const float* x  = (const float*)d_in[0];
    const float* Wq = (const float*)d_in[1];
    const float* bq = (const float*)d_in[2];
    const float* Wk = (const float*)d_in[3];
    const float* bk = (const float*)d_in[4];
    const float* Wv = (const float*)d_in[5];
    const float* bv = (const float*)d_in[6];
    const float* Wo = (const float*)d_in[7];
    const float* bo = (const float*)d_in[8];
    float* out = (float*)d_out;

    char* ws = (char*)d_ws;
    bf16* xb    = (bf16*)(ws);                // 8 MB; reused as Ob after GEMM1
    bf16* Wcat  = (bf16*)(ws + 8388608);      // 6 MB
    bf16* Wob   = (bf16*)(ws + 14680064);     // 2 MB
    float* bcat = (float*)(ws + 16777216);    // 12 KB
    bf16* QKV   = (bf16*)(ws + 16789504);     // 24 MB (V third unused)
    bf16* Vt    = (bf16*)(ws + 41955328);     // 8 MB, j-permuted layout
    bf16* Ob    = xb;                         // x no longer needed after GEMM1

    static bool s_attr_done = false;
    if (!s_attr_done) {
        (void)hipFuncSetAttribute(reinterpret_cast<const void*>(gemm192),
                                  hipFuncAttributeMaxDynamicSharedMemorySize,
                                  114688);
        (void)hipFuncSetAttribute(reinterpret_cast<const void*>(gemm128),
                                  hipFuncAttributeMaxDynamicSharedMemorySize,
                                  65536);
        s_attr_done = true;
    }

    convert_k<<<dim3(1024), dim3(256), 0, stream>>>(x, Wq, bq, Wk, bk, Wv, bv, Wo,
                                                    xb, Wcat, Wob, bcat);
    gemm192<<<dim3(N_QKV / 192, M_TOK / 256), dim3(512), 114688, stream>>>(
        xb, Wcat, bcat, QKV, Vt, M_TOK, N_QKV, FDIM);
    attn_k<<<dim3((SEQ / 128) * BB * NH), dim3(512), 0, stream>>>(QKV, Vt, Ob);
    gemm128<<<dim3(FDIM / 128, M_TOK / 128), dim3(512), 65536, stream>>>(
        Ob, Wob, bo, out, M_TOK, FDIM, FDIM);
}